// Round 4
// baseline (274.584 us; speedup 1.0000x reference)
//
#include <hip/hip_runtime.h>
#include <hip/hip_bf16.h>
#include <math.h>

constexpr int B = 32, T = 256, D = 2048, H = 16, DK = 64;
constexpr size_t BHTD = (size_t)B * H * T * DK;  // 8388608
constexpr int NC8 = (B * T * D) / 8;             // 2097152
constexpr int NW8 = (H * DK * D) / 8;            // 262144
constexpr int NB8 = (H * D) / 8;                 // 4096

typedef __attribute__((ext_vector_type(8))) short short8;
typedef __attribute__((ext_vector_type(4))) float f32x4;

#define MFMA16(a, b, c) __builtin_amdgcn_mfma_f32_16x16x32_bf16((a), (b), (c), 0, 0, 0)

// ---------------------------------------------------------------------------
// one grid-stride cast kernel: content -> c_bf; [k_w;v_w;b_w;ts_w] -> w_bf
// ---------------------------------------------------------------------------
__global__ __launch_bounds__(256) void cast_all(
    const float* __restrict__ content, const float* __restrict__ k_w,
    const float* __restrict__ v_w, const float* __restrict__ b_w,
    const float* __restrict__ ts_w, __hip_bfloat16* __restrict__ c_bf,
    __hip_bfloat16* __restrict__ w_bf) {
  const int total = NC8 + 2 * NW8 + 2 * NB8;
  int i = blockIdx.x * blockDim.x + threadIdx.x;
  const int stride = gridDim.x * blockDim.x;
  for (; i < total; i += stride) {
    const float* src;
    __hip_bfloat16* dst;
    int idx;
    if (i < NC8) { src = content; dst = c_bf; idx = i; }
    else if (i < NC8 + NW8) { src = k_w; dst = w_bf; idx = i - NC8; }
    else if (i < NC8 + 2 * NW8) {
      src = v_w; dst = w_bf + (size_t)1024 * D; idx = i - NC8 - NW8;
    } else if (i < NC8 + 2 * NW8 + NB8) {
      src = b_w; dst = w_bf + (size_t)2048 * D; idx = i - NC8 - 2 * NW8;
    } else {
      src = ts_w; dst = w_bf + (size_t)2064 * D; idx = i - NC8 - 2 * NW8 - NB8;
    }
    const float4 x = ((const float4*)src)[2 * idx];
    const float4 y = ((const float4*)src)[2 * idx + 1];
    __hip_bfloat16 tmp[8];
    tmp[0] = __float2bfloat16(x.x); tmp[1] = __float2bfloat16(x.y);
    tmp[2] = __float2bfloat16(x.z); tmp[3] = __float2bfloat16(x.w);
    tmp[4] = __float2bfloat16(y.x); tmp[5] = __float2bfloat16(y.y);
    tmp[6] = __float2bfloat16(y.z); tmp[7] = __float2bfloat16(y.w);
    *(uint4*)(dst + 8 * (size_t)idx) = *(const uint4*)tmp;
  }
}

// ---------------------------------------------------------------------------
// 256x256-tile 8-phase GEMM — unchanged.
// ---------------------------------------------------------------------------
__device__ __forceinline__ short8 ldsfrag128(const char* half_base, int row, int g) {
  return *(const short8*)(half_base + row * 128 + ((g ^ (row & 7)) << 4));
}

#define GBAR()                                   \
  do {                                           \
    asm volatile("" ::: "memory");               \
    __builtin_amdgcn_sched_barrier(0);           \
    __builtin_amdgcn_s_barrier();                \
    __builtin_amdgcn_sched_barrier(0);           \
  } while (0)

__global__ __launch_bounds__(512, 2) void gemm256(
    const __hip_bfloat16* __restrict__ A, const __hip_bfloat16* __restrict__ Wc,
    float* __restrict__ outk) {
  extern __shared__ char smem[];
  const int tid = threadIdx.x;
  const int w = tid >> 6, l = tid & 63;
  const int wm = w >> 2, wn = w & 3;
  const int fr = l & 15, fq = l >> 4;
  const int x = blockIdx.x & 7, q = (blockIdx.x >> 3) & 3, nt = blockIdx.x >> 5;
  const int mt = x * 4 + q;
  const int m0 = mt * 256, n0 = nt * 256;
  const int lrow = l >> 3;
  const int lg = ((l & 7) ^ lrow) * 8;

  auto stage = [&](const __hip_bfloat16* gbase, char* lds_half) {
#pragma unroll
    for (int r = 0; r < 2; ++r) {
      __builtin_amdgcn_global_load_lds(
          (const __attribute__((address_space(1))) void*)(
              gbase + (size_t)(r * 64 + w * 8 + lrow) * D + lg),
          (__attribute__((address_space(3))) void*)(lds_half + r * 8192 + w * 1024),
          16, 0, 0);
    }
  };
  auto issue = [&](int h) {
    if (h >= 128) return;
    const int tau = h >> 2, s = h & 3;
    const int k0 = tau * 64;
    char* base = smem + ((s < 2) ? 65536 : 0) + ((tau & 1) * 2 + (s & 1)) * 16384;
    const __hip_bfloat16* g = (s < 2)
        ? (Wc + (size_t)(n0 + (s & 1) * 128) * D + k0)
        : (A + (size_t)(m0 + (s & 1) * 128) * D + k0);
    stage(g, base);
  };

  for (int h = 0; h < 7; ++h) issue(h);
  asm volatile("s_waitcnt vmcnt(6)" ::: "memory");
  GBAR();

  f32x4 acc[8][4] = {};
  for (int tau = 0; tau < 32; ++tau) {
    const char* Ah = smem + ((tau & 1) * 2 + wm) * 16384;
    const char* Bh = smem + 65536 + ((tau & 1) * 2 + (wn >> 1)) * 16384;
    const int br0 = (wn & 1) * 64;
    short8 b0[4], b1[4], aA[2], aB[2], aC[2], aD[2];

#pragma unroll
    for (int j = 0; j < 4; ++j) {
      b0[j] = ldsfrag128(Bh, br0 + j * 16 + fr, fq);
      b1[j] = ldsfrag128(Bh, br0 + j * 16 + fr, 4 + fq);
    }
#pragma unroll
    for (int kk = 0; kk < 2; ++kk) {
      aA[kk] = ldsfrag128(Ah, 0 * 16 + fr, kk * 4 + fq);
      aB[kk] = ldsfrag128(Ah, 1 * 16 + fr, kk * 4 + fq);
    }
    issue(4 * tau + 7);
    GBAR();
    asm volatile("s_waitcnt lgkmcnt(0)" ::: "memory");
    __builtin_amdgcn_sched_barrier(0);
    __builtin_amdgcn_s_setprio(1);
#pragma unroll
    for (int j = 0; j < 4; ++j) {
      acc[0][j] = MFMA16(aA[0], b0[j], acc[0][j]);
      acc[0][j] = MFMA16(aA[1], b1[j], acc[0][j]);
      acc[1][j] = MFMA16(aB[0], b0[j], acc[1][j]);
      acc[1][j] = MFMA16(aB[1], b1[j], acc[1][j]);
    }
    __builtin_amdgcn_s_setprio(0);
    GBAR();

#pragma unroll
    for (int kk = 0; kk < 2; ++kk) {
      aA[kk] = ldsfrag128(Ah, 2 * 16 + fr, kk * 4 + fq);
      aB[kk] = ldsfrag128(Ah, 3 * 16 + fr, kk * 4 + fq);
    }
    issue(4 * tau + 8);
    GBAR();
    asm volatile("s_waitcnt lgkmcnt(0)" ::: "memory");
    __builtin_amdgcn_sched_barrier(0);
    __builtin_amdgcn_s_setprio(1);
#pragma unroll
    for (int j = 0; j < 4; ++j) {
      acc[2][j] = MFMA16(aA[0], b0[j], acc[2][j]);
      acc[2][j] = MFMA16(aA[1], b1[j], acc[2][j]);
      acc[3][j] = MFMA16(aB[0], b0[j], acc[3][j]);
      acc[3][j] = MFMA16(aB[1], b1[j], acc[3][j]);
    }
    __builtin_amdgcn_s_setprio(0);
    GBAR();

#pragma unroll
    for (int kk = 0; kk < 2; ++kk) {
      aA[kk] = ldsfrag128(Ah, 4 * 16 + fr, kk * 4 + fq);
      aB[kk] = ldsfrag128(Ah, 5 * 16 + fr, kk * 4 + fq);
      aC[kk] = ldsfrag128(Ah, 6 * 16 + fr, kk * 4 + fq);
      aD[kk] = ldsfrag128(Ah, 7 * 16 + fr, kk * 4 + fq);
    }
    issue(4 * tau + 9);
    GBAR();
    asm volatile("s_waitcnt lgkmcnt(0)" ::: "memory");
    __builtin_amdgcn_sched_barrier(0);
    __builtin_amdgcn_s_setprio(1);
#pragma unroll
    for (int j = 0; j < 4; ++j) {
      acc[4][j] = MFMA16(aA[0], b0[j], acc[4][j]);
      acc[4][j] = MFMA16(aA[1], b1[j], acc[4][j]);
      acc[5][j] = MFMA16(aB[0], b0[j], acc[5][j]);
      acc[5][j] = MFMA16(aB[1], b1[j], acc[5][j]);
    }
    __builtin_amdgcn_s_setprio(0);
    GBAR();

    issue(4 * tau + 10);
    GBAR();
    __builtin_amdgcn_s_setprio(1);
#pragma unroll
    for (int j = 0; j < 4; ++j) {
      acc[6][j] = MFMA16(aC[0], b0[j], acc[6][j]);
      acc[6][j] = MFMA16(aC[1], b1[j], acc[6][j]);
      acc[7][j] = MFMA16(aD[0], b0[j], acc[7][j]);
      acc[7][j] = MFMA16(aD[1], b1[j], acc[7][j]);
    }
    __builtin_amdgcn_s_setprio(0);
    if (tau < 30) asm volatile("s_waitcnt vmcnt(6)" ::: "memory");
    else asm volatile("s_waitcnt vmcnt(0)" ::: "memory");
    GBAR();
  }

#pragma unroll
  for (int i = 0; i < 8; ++i) {
    const int mbase = m0 + wm * 128 + i * 16 + fq * 4;
#pragma unroll
    for (int j = 0; j < 4; ++j) {
      const int n = n0 + wn * 64 + j * 16 + fr;
      const int h = (n >> 6) & 15, dk = n & 63;
      float* dst = outk + (size_t)(n >> 10) * BHTD;
#pragma unroll
      for (int r = 0; r < 4; ++r) {
        const int mm = mbase + r;
        const int b = mm >> 8, t = mm & 255;
        dst[(((size_t)b * H + h) * T + t) * DK + dk] = acc[i][j][r];
      }
    }
  }
}

// ---------------------------------------------------------------------------
// beta/gamma skinny GEMM v3: 512 blocks x 256 thr; each block = 16 rows,
// 4 waves = 4-way K-split (512 K each, 16 iters), LDS partial reduce.
// 8 waves/CU of short latency-tolerant work.
// ---------------------------------------------------------------------------
__global__ __launch_bounds__(256) void bg_gemm(
    const __hip_bfloat16* __restrict__ A, const __hip_bfloat16* __restrict__ Wbg,
    const float* __restrict__ b_b, const float* __restrict__ ts_b,
    const float* __restrict__ hd, float* __restrict__ beta_out,
    float* __restrict__ gamma_out) {
  __shared__ float part[3][64][8];
  const int tid = threadIdx.x, w = tid >> 6, l = tid & 63;
  const int fr = l & 15, fq = l >> 4;
  const int m0 = blockIdx.x * 16;
  f32x4 acc0 = {0.f, 0.f, 0.f, 0.f}, acc1 = {0.f, 0.f, 0.f, 0.f};
  const __hip_bfloat16* ar = A + (size_t)(m0 + fr) * D + fq * 8 + w * 512;
  const __hip_bfloat16* br = Wbg + (size_t)fr * D + fq * 8 + w * 512;
  const __hip_bfloat16* gr = Wbg + (size_t)(16 + fr) * D + fq * 8 + w * 512;
#pragma unroll 4
  for (int k0 = 0; k0 < 512; k0 += 32) {
    short8 af = *(const short8*)(ar + k0);
    short8 bfb = *(const short8*)(br + k0);
    short8 bfg = *(const short8*)(gr + k0);
    acc0 = MFMA16(af, bfb, acc0);
    acc1 = MFMA16(af, bfg, acc1);
  }
  if (w > 0) {
#pragma unroll
    for (int r = 0; r < 4; ++r) {
      part[w - 1][l][r] = acc0[r];
      part[w - 1][l][4 + r] = acc1[r];
    }
  }
  __syncthreads();
  if (w == 0) {
#pragma unroll
    for (int p = 0; p < 3; ++p)
#pragma unroll
      for (int r = 0; r < 4; ++r) {
        acc0[r] += part[p][l][r];
        acc1[r] += part[p][l][4 + r];
      }
    const float bb = b_b[fr], bg = ts_b[fr] + hd[fr];
#pragma unroll
    for (int r = 0; r < 4; ++r) {
      const int mm = m0 + fq * 4 + r;
      const int b = mm >> 8, t = mm & 255;
      const size_t oo = ((size_t)b * H + fr) * T + t;
      beta_out[oo] = 1.f / (1.f + __expf(-(acc0[r] + bb)));
      gamma_out[oo] = 1.f / (1.f + __expf(-(acc1[r] + bg)));
    }
  }
}

// ---------------------------------------------------------------------------
// Chunked solve v7: v-dimension split 2-way (1024 blocks = 512 bh x 2 vs),
// LDS lifetime overlays (kCb/Uu, Mb/Ub, wpart/Ss) -> 40960 B = 4 blocks/CU,
// 16 waves/CU. Per-column arithmetic identical to unsplit (bit-identical).
// P2/P4 wave mapping: wv = w&1 (v-16-tile), wd = w>>1 (d-half).
// P3: wave owns 8 v-columns. New barrier between P1 and P2 protects the
// kCb->Uu overlay (af fragments are register-resident across it).
// ---------------------------------------------------------------------------
__device__ __forceinline__ float rdlane(float x, int j) {
  return __int_as_float(__builtin_amdgcn_readlane(__float_as_int(x), j));
}
__device__ __forceinline__ int bofs(int row, int col) {
  return row * 128 + ((((col >> 3) ^ (row & 7))) << 4) + ((col & 7) << 1);
}
__device__ __forceinline__ short8 ldsfrag(const __hip_bfloat16* base, int row, int g0) {
  return *(const short8*)((const char*)base + row * 128 + (((g0 ^ (row & 7))) << 4));
}

#define SBAR()                                           \
  do {                                                   \
    __builtin_amdgcn_sched_barrier(0);                   \
    asm volatile("s_waitcnt lgkmcnt(0)" ::: "memory");   \
    __builtin_amdgcn_s_barrier();                        \
    __builtin_amdgcn_sched_barrier(0);                   \
  } while (0)

__global__ __launch_bounds__(256, 4) void solve_write(
    const float* __restrict__ kg, const float* __restrict__ vg,
    const float* __restrict__ betag, const float* __restrict__ gammag,
    const float* __restrict__ Wold, float* __restrict__ Wnew) {
  __shared__ __hip_bfloat16 kTb[64 * 64];  // 8192: K^T[d][t], full chunk
  __shared__ char regA[9216];              // kCb [64][64]bf16 (stage..P1) / Uu f32[64][36] (P2..P3)
  __shared__ char regB[4096];              // Mb [32][64]bf16 (stage..P2) / Ub [32][64]bf16 (P3..P4)
  __shared__ float Ss[64][68];             // 17408; first 16B double as wpart (scan only)
  __shared__ float s_beta[256], s_cl[256];

  __hip_bfloat16* kCb = (__hip_bfloat16*)regA;
  float (*Uu)[36] = (float(*)[36])regA;
  __hip_bfloat16* Mb = (__hip_bfloat16*)regB;
  __hip_bfloat16* Ub = (__hip_bfloat16*)regB;
  float* wpart = (float*)Ss;

  const int tid = threadIdx.x;
  const int bh = blockIdx.x & 511, vs = blockIdx.x >> 9;
  const size_t base = (size_t)bh * T * DK;
  const int lane = tid & 63, w = tid >> 6;
  const int fr = lane & 15, fq = lane >> 4;
  const int wv = w & 1, wd = w >> 1;
  const int sr = tid >> 2, sp = tid & 3;

  s_beta[tid] = betag[(size_t)bh * T + tid];
  // parallel inclusive scan of log(gamma)
  float xls = __logf(fmaxf(gammag[(size_t)bh * T + tid], 1e-8f));
#pragma unroll
  for (int d = 1; d < 64; d <<= 1) {
    float y = __shfl_up(xls, d, 64);
    if (lane >= d) xls += y;
  }
  if (lane == 63) wpart[w] = xls;
  __syncthreads();
  {
    float off = 0.f;
    if (w > 0) off += wpart[0];
    if (w > 1) off += wpart[1];
    if (w > 2) off += wpart[2];
    s_cl[tid] = xls + off;
  }
  // M^T state (v-slice): mreg[jj][r] = M^T[v][d],
  // v = 32*vs + 16*wv + fq*4 + r, d = 16*(2*wd+jj) + fr.
  f32x4 mreg[2];
  {
    const float* Wo = Wold + (size_t)bh * DK * DK + (size_t)(32 * vs) * DK;
#pragma unroll
    for (int jj = 0; jj < 2; ++jj)
#pragma unroll
      for (int r = 0; r < 4; ++r)
        mreg[jj][r] = Wo[(size_t)(16 * wv + fq * 4 + r) * DK + 16 * (2 * wd + jj) + fr];
  }
  // chunk-0 prefetch (in flight across SBAR)
  const float4* kgp = (const float4*)(kg + base + (size_t)sr * DK) + sp * 4;
  const float* vbase = vg + base + (size_t)(16 * w + fq * 4) * DK + 32 * vs + fr;
  float4 kx0 = kgp[0], kx1 = kgp[1], kx2 = kgp[2], kx3 = kgp[3];
  float vv[8];
#pragma unroll
  for (int jj = 0; jj < 2; ++jj)
#pragma unroll
    for (int r = 0; r < 4; ++r)
      vv[4 * jj + r] = vbase[(size_t)r * DK + 16 * jj];
  SBAR();  // s_cl visible; wpart dead; global prefetches stay pending

  for (int c = 0; c < 4; ++c) {
    const int c0 = c * 64;
    const float oc = (c == 0) ? 0.f : s_cl[c0 - 1];
    const float on = s_cl[c0 + 63];

    {  // ---- stage: Mb dump; normalize prefetched k row; write kCb + kTb ----
#pragma unroll
      for (int jj = 0; jj < 2; ++jj)
#pragma unroll
        for (int rr = 0; rr < 4; ++rr) {
          __hip_bfloat16 h = __float2bfloat16(mreg[jj][rr]);
          *(short*)((char*)Mb + bofs(16 * wv + fq * 4 + rr, 16 * (2 * wd + jj) + fr)) =
              *(short*)&h;
        }
      const float4 x0 = kx0, x1 = kx1, x2 = kx2, x3 = kx3;
      float nrm = x0.x * x0.x + x0.y * x0.y + x0.z * x0.z + x0.w * x0.w +
                  x1.x * x1.x + x1.y * x1.y + x1.z * x1.z + x1.w * x1.w +
                  x2.x * x2.x + x2.y * x2.y + x2.z * x2.z + x2.w * x2.w +
                  x3.x * x3.x + x3.y * x3.y + x3.z * x3.z + x3.w * x3.w;
      nrm += __shfl_xor(nrm, 1, 64);
      nrm += __shfl_xor(nrm, 2, 64);
      const float rn = 1.f / fmaxf(sqrtf(nrm), 1e-12f);
      float kvf[16] = {x0.x * rn, x0.y * rn, x0.z * rn, x0.w * rn,
                       x1.x * rn, x1.y * rn, x1.z * rn, x1.w * rn,
                       x2.x * rn, x2.y * rn, x2.z * rn, x2.w * rn,
                       x3.x * rn, x3.y * rn, x3.z * rn, x3.w * rn};
      short kb[16];
#pragma unroll
      for (int u = 0; u < 16; ++u) {
        __hip_bfloat16 h = __float2bfloat16(kvf[u]);
        kb[u] = *(short*)&h;
      }
      *(short8*)((char*)kCb + sr * 128 + (((2 * sp) ^ (sr & 7)) << 4)) = *(short8*)&kb[0];
      *(short8*)((char*)kCb + sr * 128 + (((2 * sp + 1) ^ (sr & 7)) << 4)) = *(short8*)&kb[8];
#pragma unroll
      for (int u = 0; u < 16; ++u)
        *(short*)((char*)kTb + bofs(16 * sp + u, sr)) = kb[u];
    }
    SBAR();

    // ---- P1: S = K K^T (full 64x64); wave w owns t-rows 16w..16w+15 ----
    const short8 af0 = ldsfrag(kCb, 16 * w + fr, fq);
    const short8 af1 = ldsfrag(kCb, 16 * w + fr, 4 + fq);
    {
      const f32x4 zero = {0.f, 0.f, 0.f, 0.f};
#pragma unroll
      for (int j = 0; j < 4; ++j) {
        short8 b0 = ldsfrag(kCb, 16 * j + fr, fq);
        short8 b1 = ldsfrag(kCb, 16 * j + fr, 4 + fq);
        f32x4 s4 = MFMA16(af0, b0, zero);
        s4 = MFMA16(af1, b1, s4);
#pragma unroll
        for (int r = 0; r < 4; ++r) Ss[16 * w + fq * 4 + r][16 * j + fr] = s4[r];
      }
    }
    SBAR();  // kCb dead (af held in regs); Uu may now overwrite regA

    {  // ---- P2: U = V - eci*K M (v-slice cols 0..31); then prefetch next chunk ----
      const f32x4 zero = {0.f, 0.f, 0.f, 0.f};
      float eci[4];
#pragma unroll
      for (int r = 0; r < 4; ++r) {
        const int gi = c0 + 16 * w + fq * 4 + r;
        eci[r] = __expf((gi == 0) ? 0.f : s_cl[gi - 1] - oc);
      }
#pragma unroll
      for (int jj = 0; jj < 2; ++jj) {
        short8 m0 = ldsfrag(Mb, 16 * jj + fr, fq);
        short8 m1 = ldsfrag(Mb, 16 * jj + fr, 4 + fq);
        f32x4 u4 = MFMA16(af0, m0, zero);
        u4 = MFMA16(af1, m1, u4);
#pragma unroll
        for (int r = 0; r < 4; ++r) {
          const int t = 16 * w + fq * 4 + r;
          Uu[t][16 * jj + fr] = vv[4 * jj + r] - eci[r] * u4[r];
        }
      }
      if (c < 3) {  // prefetch chunk c+1 (lands during P3/P4)
        const float4* kn = kgp + (size_t)(c + 1) * 1024;
        kx0 = kn[0]; kx1 = kn[1]; kx2 = kn[2]; kx3 = kn[3];
#pragma unroll
        for (int jj = 0; jj < 2; ++jj)
#pragma unroll
          for (int r = 0; r < 4; ++r)
            vv[4 * jj + r] = vbase[(size_t)(c0 + 64 + r) * DK + 16 * jj];
      }
    }
    SBAR();

    {  // ---- P3: serial substitution; wave w owns v-cols [8w, 8w+8) ----
      const int gi = c0 + lane;
      const int v0 = 8 * w;
      float rhs[8];
      *(float4*)&rhs[0] = *(const float4*)&Uu[lane][v0];
      *(float4*)&rhs[4] = *(const float4*)&Uu[lane][v0 + 4];
      const float ci = (gi == 0) ? 0.f : s_cl[gi - 1] - oc;
      const float ecl = __expf(ci);
      const float wgt = s_beta[gi] * __expf(-(s_cl[gi] - oc));
      for (int j = 0; j < 63; ++j) {
        const float wj = rdlane(wgt, j);
        const float sv = Ss[j][lane];  // symmetric: = S[lane][j]
        const float co = (lane > j) ? ecl * wj * sv : 0.f;
#pragma unroll
        for (int u = 0; u < 8; ++u) rhs[u] -= co * rdlane(rhs[u], j);
      }
      const float ul = wgt * __expf(on - oc);
#pragma unroll
      for (int u = 0; u < 8; ++u) {
        __hip_bfloat16 h = __float2bfloat16(ul * rhs[u]);
        *(short*)((char*)Ub + bofs(v0 + u, lane)) = *(short*)&h;
      }
    }
    SBAR();

    {  // ---- P4: M^T = rc*M^T + U^T K (v-slice); wave (wv, wd) ----
      const float rc = __expf(on - oc);
      const short8 a0 = ldsfrag(Ub, 16 * wv + fr, fq);
      const short8 a1 = ldsfrag(Ub, 16 * wv + fr, 4 + fq);
#pragma unroll
      for (int jj = 0; jj < 2; ++jj) {
        short8 b0 = ldsfrag(kTb, 16 * (2 * wd + jj) + fr, fq);
        short8 b1 = ldsfrag(kTb, 16 * (2 * wd + jj) + fr, 4 + fq);
        f32x4 c4;
#pragma unroll
        for (int r = 0; r < 4; ++r) c4[r] = rc * mreg[jj][r];
        c4 = MFMA16(a0, b0, c4);
        c4 = MFMA16(a1, b1, c4);
        mreg[jj] = c4;
      }
    }
    SBAR();  // protect kTb/Mb/Ub before next stage
  }
  // ---- epilogue: W_new v-slice ----
  {
    float* op = Wnew + (size_t)bh * DK * DK;
#pragma unroll
    for (int jj = 0; jj < 2; ++jj)
#pragma unroll
      for (int r = 0; r < 4; ++r)
        op[(size_t)(32 * vs + 16 * wv + fq * 4 + r) * DK + 16 * (2 * wd + jj) + fr] =
            mreg[jj][r];
  }
}

// ---------------------------------------------------------------------------
extern "C" void kernel_launch(void* const* d_in, const int* in_sizes, int n_in,
                              void* d_out, int out_size, void* d_ws, size_t ws_size,
                              hipStream_t stream) {
  const float* W_old = (const float*)d_in[0];
  const float* content = (const float*)d_in[1];
  const float* k_w = (const float*)d_in[2];
  const float* v_w = (const float*)d_in[3];
  const float* b_w = (const float*)d_in[4];
  const float* b_b = (const float*)d_in[5];
  const float* ts_w = (const float*)d_in[6];
  const float* ts_b = (const float*)d_in[7];
  const float* hd = (const float*)d_in[8];
  float* out = (float*)d_out;

  float* ws_k = (float*)d_ws;
  float* ws_v = ws_k + BHTD;
  float* ws_beta = ws_v + BHTD;
  float* ws_gamma = ws_beta + (size_t)B * H * T;
  __hip_bfloat16* c_bf = (__hip_bfloat16*)(ws_gamma + (size_t)B * H * T);
  __hip_bfloat16* w_bf = c_bf + (size_t)B * T * D;  // 2176 x 2048 region

  static int attr_done = 0;
  if (!attr_done) {
    hipFuncSetAttribute(reinterpret_cast<const void*>(gemm256),
                        hipFuncAttributeMaxDynamicSharedMemorySize, 131072);
    attr_done = 1;
  }

  cast_all<<<2048, 256, 0, stream>>>(content, k_w, v_w, b_w, ts_w, c_bf, w_bf);
  gemm256<<<dim3(256), dim3(512), 131072, stream>>>(c_bf, w_bf, ws_k);
  bg_gemm<<<dim3(512), 256, 0, stream>>>(c_bf, w_bf + (size_t)2048 * D,
                                         b_b, ts_b, hd, ws_beta, ws_gamma);
  solve_write<<<dim3(2 * B * H), 256, 0, stream>>>(ws_k, ws_v, ws_beta, ws_gamma,
                                                   W_old, out);
}

// Round 5
// 263.694 us; speedup vs baseline: 1.0413x; 1.0413x over previous
//
#include <hip/hip_runtime.h>
#include <hip/hip_bf16.h>
#include <math.h>

constexpr int B = 32, T = 256, D = 2048, H = 16, DK = 64;
constexpr size_t BHTD = (size_t)B * H * T * DK;  // 8388608
constexpr int NC8 = (B * T * D) / 8;             // 2097152
constexpr int NW8 = (H * DK * D) / 8;            // 262144
constexpr int NB8 = (H * D) / 8;                 // 4096

typedef __attribute__((ext_vector_type(8))) short short8;
typedef __attribute__((ext_vector_type(4))) float f32x4;

#define MFMA16(a, b, c) __builtin_amdgcn_mfma_f32_16x16x32_bf16((a), (b), (c), 0, 0, 0)

// ---------------------------------------------------------------------------
// one grid-stride cast kernel: content -> c_bf; [k_w;v_w;b_w;ts_w] -> w_bf
// ---------------------------------------------------------------------------
__global__ __launch_bounds__(256) void cast_all(
    const float* __restrict__ content, const float* __restrict__ k_w,
    const float* __restrict__ v_w, const float* __restrict__ b_w,
    const float* __restrict__ ts_w, __hip_bfloat16* __restrict__ c_bf,
    __hip_bfloat16* __restrict__ w_bf) {
  const int total = NC8 + 2 * NW8 + 2 * NB8;
  int i = blockIdx.x * blockDim.x + threadIdx.x;
  const int stride = gridDim.x * blockDim.x;
  for (; i < total; i += stride) {
    const float* src;
    __hip_bfloat16* dst;
    int idx;
    if (i < NC8) { src = content; dst = c_bf; idx = i; }
    else if (i < NC8 + NW8) { src = k_w; dst = w_bf; idx = i - NC8; }
    else if (i < NC8 + 2 * NW8) {
      src = v_w; dst = w_bf + (size_t)1024 * D; idx = i - NC8 - NW8;
    } else if (i < NC8 + 2 * NW8 + NB8) {
      src = b_w; dst = w_bf + (size_t)2048 * D; idx = i - NC8 - 2 * NW8;
    } else {
      src = ts_w; dst = w_bf + (size_t)2064 * D; idx = i - NC8 - 2 * NW8 - NB8;
    }
    const float4 x = ((const float4*)src)[2 * idx];
    const float4 y = ((const float4*)src)[2 * idx + 1];
    __hip_bfloat16 tmp[8];
    tmp[0] = __float2bfloat16(x.x); tmp[1] = __float2bfloat16(x.y);
    tmp[2] = __float2bfloat16(x.z); tmp[3] = __float2bfloat16(x.w);
    tmp[4] = __float2bfloat16(y.x); tmp[5] = __float2bfloat16(y.y);
    tmp[6] = __float2bfloat16(y.z); tmp[7] = __float2bfloat16(y.w);
    *(uint4*)(dst + 8 * (size_t)idx) = *(const uint4*)tmp;
  }
}

// ---------------------------------------------------------------------------
// 256x256-tile 8-phase GEMM with fused beta/gamma tail phase.
// After each block's epilogue, it computes 32 rows of beta/gamma using the
// exact bg_gemm-v3 arithmetic (4-way K-split x 512, LDS partial reduce,
// p-ordered combine) => bit-identical outputs, no separate launch, and the
// work drain-fills behind the gemm's staggered block completion.
// ---------------------------------------------------------------------------
__device__ __forceinline__ short8 ldsfrag128(const char* half_base, int row, int g) {
  return *(const short8*)(half_base + row * 128 + ((g ^ (row & 7)) << 4));
}

#define GBAR()                                   \
  do {                                           \
    asm volatile("" ::: "memory");               \
    __builtin_amdgcn_sched_barrier(0);           \
    __builtin_amdgcn_s_barrier();                \
    __builtin_amdgcn_sched_barrier(0);           \
  } while (0)

__global__ __launch_bounds__(512, 2) void gemm_bg(
    const __hip_bfloat16* __restrict__ A, const __hip_bfloat16* __restrict__ Wc,
    float* __restrict__ outk, const float* __restrict__ b_b,
    const float* __restrict__ ts_b, const float* __restrict__ hd,
    float* __restrict__ beta_out, float* __restrict__ gamma_out) {
  extern __shared__ char smem[];
  const int tid = threadIdx.x;
  const int w = tid >> 6, l = tid & 63;
  const int wm = w >> 2, wn = w & 3;
  const int fr = l & 15, fq = l >> 4;
  const int x = blockIdx.x & 7, q = (blockIdx.x >> 3) & 3, nt = blockIdx.x >> 5;
  const int mt = x * 4 + q;
  const int m0 = mt * 256, n0 = nt * 256;
  const int lrow = l >> 3;
  const int lg = ((l & 7) ^ lrow) * 8;

  auto stage = [&](const __hip_bfloat16* gbase, char* lds_half) {
#pragma unroll
    for (int r = 0; r < 2; ++r) {
      __builtin_amdgcn_global_load_lds(
          (const __attribute__((address_space(1))) void*)(
              gbase + (size_t)(r * 64 + w * 8 + lrow) * D + lg),
          (__attribute__((address_space(3))) void*)(lds_half + r * 8192 + w * 1024),
          16, 0, 0);
    }
  };
  auto issue = [&](int h) {
    if (h >= 128) return;
    const int tau = h >> 2, s = h & 3;
    const int k0 = tau * 64;
    char* base = smem + ((s < 2) ? 65536 : 0) + ((tau & 1) * 2 + (s & 1)) * 16384;
    const __hip_bfloat16* g = (s < 2)
        ? (Wc + (size_t)(n0 + (s & 1) * 128) * D + k0)
        : (A + (size_t)(m0 + (s & 1) * 128) * D + k0);
    stage(g, base);
  };

  for (int h = 0; h < 7; ++h) issue(h);
  asm volatile("s_waitcnt vmcnt(6)" ::: "memory");
  GBAR();

  f32x4 acc[8][4] = {};
  for (int tau = 0; tau < 32; ++tau) {
    const char* Ah = smem + ((tau & 1) * 2 + wm) * 16384;
    const char* Bh = smem + 65536 + ((tau & 1) * 2 + (wn >> 1)) * 16384;
    const int br0 = (wn & 1) * 64;
    short8 b0[4], b1[4], aA[2], aB[2], aC[2], aD[2];

#pragma unroll
    for (int j = 0; j < 4; ++j) {
      b0[j] = ldsfrag128(Bh, br0 + j * 16 + fr, fq);
      b1[j] = ldsfrag128(Bh, br0 + j * 16 + fr, 4 + fq);
    }
#pragma unroll
    for (int kk = 0; kk < 2; ++kk) {
      aA[kk] = ldsfrag128(Ah, 0 * 16 + fr, kk * 4 + fq);
      aB[kk] = ldsfrag128(Ah, 1 * 16 + fr, kk * 4 + fq);
    }
    issue(4 * tau + 7);
    GBAR();
    asm volatile("s_waitcnt lgkmcnt(0)" ::: "memory");
    __builtin_amdgcn_sched_barrier(0);
    __builtin_amdgcn_s_setprio(1);
#pragma unroll
    for (int j = 0; j < 4; ++j) {
      acc[0][j] = MFMA16(aA[0], b0[j], acc[0][j]);
      acc[0][j] = MFMA16(aA[1], b1[j], acc[0][j]);
      acc[1][j] = MFMA16(aB[0], b0[j], acc[1][j]);
      acc[1][j] = MFMA16(aB[1], b1[j], acc[1][j]);
    }
    __builtin_amdgcn_s_setprio(0);
    GBAR();

#pragma unroll
    for (int kk = 0; kk < 2; ++kk) {
      aA[kk] = ldsfrag128(Ah, 2 * 16 + fr, kk * 4 + fq);
      aB[kk] = ldsfrag128(Ah, 3 * 16 + fr, kk * 4 + fq);
    }
    issue(4 * tau + 8);
    GBAR();
    asm volatile("s_waitcnt lgkmcnt(0)" ::: "memory");
    __builtin_amdgcn_sched_barrier(0);
    __builtin_amdgcn_s_setprio(1);
#pragma unroll
    for (int j = 0; j < 4; ++j) {
      acc[2][j] = MFMA16(aA[0], b0[j], acc[2][j]);
      acc[2][j] = MFMA16(aA[1], b1[j], acc[2][j]);
      acc[3][j] = MFMA16(aB[0], b0[j], acc[3][j]);
      acc[3][j] = MFMA16(aB[1], b1[j], acc[3][j]);
    }
    __builtin_amdgcn_s_setprio(0);
    GBAR();

#pragma unroll
    for (int kk = 0; kk < 2; ++kk) {
      aA[kk] = ldsfrag128(Ah, 4 * 16 + fr, kk * 4 + fq);
      aB[kk] = ldsfrag128(Ah, 5 * 16 + fr, kk * 4 + fq);
      aC[kk] = ldsfrag128(Ah, 6 * 16 + fr, kk * 4 + fq);
      aD[kk] = ldsfrag128(Ah, 7 * 16 + fr, kk * 4 + fq);
    }
    issue(4 * tau + 9);
    GBAR();
    asm volatile("s_waitcnt lgkmcnt(0)" ::: "memory");
    __builtin_amdgcn_sched_barrier(0);
    __builtin_amdgcn_s_setprio(1);
#pragma unroll
    for (int j = 0; j < 4; ++j) {
      acc[4][j] = MFMA16(aA[0], b0[j], acc[4][j]);
      acc[4][j] = MFMA16(aA[1], b1[j], acc[4][j]);
      acc[5][j] = MFMA16(aB[0], b0[j], acc[5][j]);
      acc[5][j] = MFMA16(aB[1], b1[j], acc[5][j]);
    }
    __builtin_amdgcn_s_setprio(0);
    GBAR();

    issue(4 * tau + 10);
    GBAR();
    __builtin_amdgcn_s_setprio(1);
#pragma unroll
    for (int j = 0; j < 4; ++j) {
      acc[6][j] = MFMA16(aC[0], b0[j], acc[6][j]);
      acc[6][j] = MFMA16(aC[1], b1[j], acc[6][j]);
      acc[7][j] = MFMA16(aD[0], b0[j], acc[7][j]);
      acc[7][j] = MFMA16(aD[1], b1[j], acc[7][j]);
    }
    __builtin_amdgcn_s_setprio(0);
    if (tau < 30) asm volatile("s_waitcnt vmcnt(6)" ::: "memory");
    else asm volatile("s_waitcnt vmcnt(0)" ::: "memory");
    GBAR();
  }

  // ---- epilogue: scatter f32 to (b,h,t,dk) ----
#pragma unroll
  for (int i = 0; i < 8; ++i) {
    const int mbase = m0 + wm * 128 + i * 16 + fq * 4;
#pragma unroll
    for (int j = 0; j < 4; ++j) {
      const int n = n0 + wn * 64 + j * 16 + fr;
      const int h = (n >> 6) & 15, dk = n & 63;
      float* dst = outk + (size_t)(n >> 10) * BHTD;
#pragma unroll
      for (int r = 0; r < 4; ++r) {
        const int mm = mbase + r;
        const int b = mm >> 8, t = mm & 255;
        dst[(((size_t)b * H + h) * T + t) * DK + dk] = acc[i][j][r];
      }
    }
  }

  // ---- bg tail: 32 rows per block; waves (half = w>>2) x (kw = w&3) ----
  {
    const __hip_bfloat16* Wbg = Wc + (size_t)2048 * D;
    const int kw = w & 3, half = w >> 2;
    const int m0b = blockIdx.x * 32 + half * 16;
    f32x4 acc0 = {0.f, 0.f, 0.f, 0.f}, acc1 = {0.f, 0.f, 0.f, 0.f};
    const __hip_bfloat16* ar = A + (size_t)(m0b + fr) * D + fq * 8 + kw * 512;
    const __hip_bfloat16* br = Wbg + (size_t)fr * D + fq * 8 + kw * 512;
    const __hip_bfloat16* gr = Wbg + (size_t)(16 + fr) * D + fq * 8 + kw * 512;
#pragma unroll 4
    for (int k0 = 0; k0 < 512; k0 += 32) {
      short8 af = *(const short8*)(ar + k0);
      short8 bfb = *(const short8*)(br + k0);
      short8 bfg = *(const short8*)(gr + k0);
      acc0 = MFMA16(af, bfb, acc0);
      acc1 = MFMA16(af, bfg, acc1);
    }
    float* part = (float*)smem;  // [half][kw-1][l][8]
    if (kw > 0) {
      float* pp = part + (((size_t)half * 3 + (kw - 1)) * 64 + l) * 8;
#pragma unroll
      for (int r = 0; r < 4; ++r) {
        pp[r] = acc0[r];
        pp[4 + r] = acc1[r];
      }
    }
    __syncthreads();
    if (kw == 0) {
#pragma unroll
      for (int p = 0; p < 3; ++p) {
        const float* pp = part + (((size_t)half * 3 + p) * 64 + l) * 8;
#pragma unroll
        for (int r = 0; r < 4; ++r) {
          acc0[r] += pp[r];
          acc1[r] += pp[4 + r];
        }
      }
      const float bb = b_b[fr], bg = ts_b[fr] + hd[fr];
#pragma unroll
      for (int r = 0; r < 4; ++r) {
        const int mm = m0b + fq * 4 + r;
        const int b = mm >> 8, t = mm & 255;
        const size_t oo = ((size_t)b * H + fr) * T + t;
        beta_out[oo] = 1.f / (1.f + __expf(-(acc0[r] + bb)));
        gamma_out[oo] = 1.f / (1.f + __expf(-(acc1[r] + bg)));
      }
    }
  }
}

// ---------------------------------------------------------------------------
// Chunked solve v5 (revert to best measured: 70.2 us in R1).
// P1/P2/P4 on MFMA (bf16 operands, f32 accum), M^T state in regs,
// P3 serial substitution in f32 (readlane); wave-parallel log-gamma scan.
// ---------------------------------------------------------------------------
__device__ __forceinline__ float rdlane(float x, int j) {
  return __int_as_float(__builtin_amdgcn_readlane(__float_as_int(x), j));
}
__device__ __forceinline__ int bofs(int row, int col) {
  return row * 128 + ((((col >> 3) ^ (row & 7))) << 4) + ((col & 7) << 1);
}
__device__ __forceinline__ short8 ldsfrag(const __hip_bfloat16* base, int row, int g0) {
  return *(const short8*)((const char*)base + row * 128 + (((g0 ^ (row & 7))) << 4));
}

__global__ __launch_bounds__(256, 2) void solve_write(
    const float* __restrict__ kg, const float* __restrict__ vg,
    const float* __restrict__ betag, const float* __restrict__ gammag,
    const float* __restrict__ Wold, float* __restrict__ Wnew) {
  __shared__ __hip_bfloat16 kCb[64 * 64];
  __shared__ __hip_bfloat16 kTb[64 * 64];
  __shared__ __hip_bfloat16 Mb[64 * 64];
  __shared__ __hip_bfloat16 Ub[64 * 64];
  __shared__ float Ss[64][68];
  __shared__ float Uu[64][68];
  __shared__ float s_beta[256], s_cl[256];
  __shared__ float wpart[4];

  const int tid = threadIdx.x;
  const int bh = blockIdx.x;
  const size_t base = (size_t)bh * T * DK;
  const int lane = tid & 63, w = tid >> 6;
  const int fr = lane & 15, fq = lane >> 4;

  s_beta[tid] = betag[(size_t)bh * T + tid];
  float xls = __logf(fmaxf(gammag[(size_t)bh * T + tid], 1e-8f));
#pragma unroll
  for (int d = 1; d < 64; d <<= 1) {
    float y = __shfl_up(xls, d, 64);
    if (lane >= d) xls += y;
  }
  if (lane == 63) wpart[w] = xls;
  __syncthreads();
  {
    float off = 0.f;
    if (w > 0) off += wpart[0];
    if (w > 1) off += wpart[1];
    if (w > 2) off += wpart[2];
    s_cl[tid] = xls + off;
  }
  f32x4 mreg[4];
  {
    const float* Wo = Wold + (size_t)bh * DK * DK;
#pragma unroll
    for (int j = 0; j < 4; ++j)
#pragma unroll
      for (int r = 0; r < 4; ++r)
        mreg[j][r] = Wo[(size_t)(16 * w + fq * 4 + r) * DK + 16 * j + fr];
  }
  __syncthreads();

  for (int c = 0; c < 4; ++c) {
    const int c0 = c * 64;
    const float oc = (c == 0) ? 0.f : s_cl[c0 - 1];
    const float on = s_cl[c0 + 63];

    {  // ---- stage: normalize k row, write kCb + kTb; dump mreg -> Mb ----
      const int r = tid >> 2, p = tid & 3;
      const float4* kp = (const float4*)(kg + base + (size_t)(c0 + r) * DK + p * 16);
      float4 x0 = kp[0], x1 = kp[1], x2 = kp[2], x3 = kp[3];
      float nrm = x0.x * x0.x + x0.y * x0.y + x0.z * x0.z + x0.w * x0.w +
                  x1.x * x1.x + x1.y * x1.y + x1.z * x1.z + x1.w * x1.w +
                  x2.x * x2.x + x2.y * x2.y + x2.z * x2.z + x2.w * x2.w +
                  x3.x * x3.x + x3.y * x3.y + x3.z * x3.z + x3.w * x3.w;
      nrm += __shfl_xor(nrm, 1, 64);
      nrm += __shfl_xor(nrm, 2, 64);
      const float rn = 1.f / fmaxf(sqrtf(nrm), 1e-12f);
      float kvf[16] = {x0.x * rn, x0.y * rn, x0.z * rn, x0.w * rn,
                       x1.x * rn, x1.y * rn, x1.z * rn, x1.w * rn,
                       x2.x * rn, x2.y * rn, x2.z * rn, x2.w * rn,
                       x3.x * rn, x3.y * rn, x3.z * rn, x3.w * rn};
      short kb[16];
#pragma unroll
      for (int u = 0; u < 16; ++u) {
        __hip_bfloat16 h = __float2bfloat16(kvf[u]);
        kb[u] = *(short*)&h;
      }
      *(short8*)((char*)kCb + r * 128 + (((2 * p) ^ (r & 7)) << 4)) = *(short8*)&kb[0];
      *(short8*)((char*)kCb + r * 128 + (((2 * p + 1) ^ (r & 7)) << 4)) = *(short8*)&kb[8];
#pragma unroll
      for (int u = 0; u < 16; ++u)
        *(short*)((char*)kTb + bofs(16 * p + u, r)) = kb[u];
#pragma unroll
      for (int j = 0; j < 4; ++j)
#pragma unroll
        for (int rr = 0; rr < 4; ++rr) {
          __hip_bfloat16 h = __float2bfloat16(mreg[j][rr]);
          *(short*)((char*)Mb + bofs(16 * w + fq * 4 + rr, 16 * j + fr)) = *(short*)&h;
        }
    }
    __syncthreads();

    {  // ---- P1 + P2 via MFMA; wave w owns rows 16w..16w+15 ----
      const short8 af0 = ldsfrag(kCb, 16 * w + fr, fq);
      const short8 af1 = ldsfrag(kCb, 16 * w + fr, 4 + fq);
      const f32x4 zero = {0.f, 0.f, 0.f, 0.f};
#pragma unroll
      for (int j = 0; j < 4; ++j) {
        short8 b0 = ldsfrag(kCb, 16 * j + fr, fq);
        short8 b1 = ldsfrag(kCb, 16 * j + fr, 4 + fq);
        f32x4 s4 = MFMA16(af0, b0, zero);
        s4 = MFMA16(af1, b1, s4);
#pragma unroll
        for (int r = 0; r < 4; ++r) Ss[16 * w + fq * 4 + r][16 * j + fr] = s4[r];
      }
      float eci[4];
#pragma unroll
      for (int r = 0; r < 4; ++r) {
        const int gi = c0 + 16 * w + fq * 4 + r;
        eci[r] = __expf((gi == 0) ? 0.f : s_cl[gi - 1] - oc);
      }
#pragma unroll
      for (int j = 0; j < 4; ++j) {
        short8 m0 = ldsfrag(Mb, 16 * j + fr, fq);
        short8 m1 = ldsfrag(Mb, 16 * j + fr, 4 + fq);
        f32x4 u4 = MFMA16(af0, m0, zero);
        u4 = MFMA16(af1, m1, u4);
#pragma unroll
        for (int r = 0; r < 4; ++r) {
          const int t = 16 * w + fq * 4 + r;
          const float vv = vg[base + (size_t)(c0 + t) * DK + 16 * j + fr];
          Uu[t][16 * j + fr] = vv - eci[r] * u4[r];
        }
      }
    }
    __syncthreads();

    {  // ---- P3: serial substitution; wave w owns v-slice [16w,16w+16) ----
      const int gi = c0 + lane;
      const int v0 = w * 16;
      float rhs[16];
#pragma unroll
      for (int u = 0; u < 4; ++u)
        *(float4*)&rhs[4 * u] = *(const float4*)&Uu[lane][v0 + 4 * u];
      const float ci = (gi == 0) ? 0.f : s_cl[gi - 1] - oc;
      const float ecl = __expf(ci);
      const float wgt = s_beta[gi] * __expf(-(s_cl[gi] - oc));
      for (int j = 0; j < 63; ++j) {
        const float wj = rdlane(wgt, j);
        const float sv = Ss[j][lane];
        const float co = (lane > j) ? ecl * wj * sv : 0.f;
#pragma unroll
        for (int u = 0; u < 16; ++u) rhs[u] -= co * rdlane(rhs[u], j);
      }
      const float ul = wgt * __expf(on - oc);
#pragma unroll
      for (int u = 0; u < 16; ++u) {
        __hip_bfloat16 h = __float2bfloat16(ul * rhs[u]);
        *(short*)((char*)Ub + bofs(v0 + u, lane)) = *(short*)&h;
      }
    }
    __syncthreads();

    {  // ---- P4: M^T = rc*M^T + U^T K via MFMA (C preloaded) ----
      const float rc = __expf(on - oc);
      const short8 a0 = ldsfrag(Ub, 16 * w + fr, fq);
      const short8 a1 = ldsfrag(Ub, 16 * w + fr, 4 + fq);
#pragma unroll
      for (int j = 0; j < 4; ++j) {
        short8 b0 = ldsfrag(kTb, 16 * j + fr, fq);
        short8 b1 = ldsfrag(kTb, 16 * j + fr, 4 + fq);
        f32x4 c4;
#pragma unroll
        for (int r = 0; r < 4; ++r) c4[r] = rc * mreg[j][r];
        c4 = MFMA16(a0, b0, c4);
        c4 = MFMA16(a1, b1, c4);
        mreg[j] = c4;
      }
    }
    __syncthreads();
  }
  {
    float* op = Wnew + (size_t)bh * DK * DK;
#pragma unroll
    for (int j = 0; j < 4; ++j)
#pragma unroll
      for (int r = 0; r < 4; ++r)
        op[(size_t)(16 * w + fq * 4 + r) * DK + 16 * j + fr] = mreg[j][r];
  }
}

// ---------------------------------------------------------------------------
extern "C" void kernel_launch(void* const* d_in, const int* in_sizes, int n_in,
                              void* d_out, int out_size, void* d_ws, size_t ws_size,
                              hipStream_t stream) {
  const float* W_old = (const float*)d_in[0];
  const float* content = (const float*)d_in[1];
  const float* k_w = (const float*)d_in[2];
  const float* v_w = (const float*)d_in[3];
  const float* b_w = (const float*)d_in[4];
  const float* b_b = (const float*)d_in[5];
  const float* ts_w = (const float*)d_in[6];
  const float* ts_b = (const float*)d_in[7];
  const float* hd = (const float*)d_in[8];
  float* out = (float*)d_out;

  float* ws_k = (float*)d_ws;
  float* ws_v = ws_k + BHTD;
  float* ws_beta = ws_v + BHTD;
  float* ws_gamma = ws_beta + (size_t)B * H * T;
  __hip_bfloat16* c_bf = (__hip_bfloat16*)(ws_gamma + (size_t)B * H * T);
  __hip_bfloat16* w_bf = c_bf + (size_t)B * T * D;  // 2176 x 2048 region

  static int attr_done = 0;
  if (!attr_done) {
    hipFuncSetAttribute(reinterpret_cast<const void*>(gemm_bg),
                        hipFuncAttributeMaxDynamicSharedMemorySize, 131072);
    attr_done = 1;
  }

  cast_all<<<2048, 256, 0, stream>>>(content, k_w, v_w, b_w, ts_w, c_bf, w_bf);
  gemm_bg<<<dim3(256), dim3(512), 131072, stream>>>(c_bf, w_bf, ws_k, b_b, ts_b,
                                                    hd, ws_beta, ws_gamma);
  solve_write<<<dim3(B * H), 256, 0, stream>>>(ws_k, ws_v, ws_beta, ws_gamma,
                                               W_old, out);
}